// Round 1
// baseline (599.161 us; speedup 1.0000x reference)
//
#include <hip/hip_runtime.h>
#include <hip/hip_bf16.h>

#define NR 8192
#define DIN 512
#define DD 256

typedef __attribute__((ext_vector_type(8))) short short8;
typedef __attribute__((ext_vector_type(4))) float f32x4;

static __device__ __forceinline__ unsigned short f2bf(float x) {
    __hip_bfloat16 b = __float2bfloat16(x);
    return __builtin_bit_cast(unsigned short, b);
}
static __device__ __forceinline__ float bf2f(unsigned short u) {
    unsigned v = ((unsigned)u) << 16;
    return __builtin_bit_cast(float, v);
}

// ---------------------------------------------------------------------------
// K2: h = x @ W^T  (fp32-accurate via hi/lo bf16 split, 3 MFMA terms)
// grid (128, 2), block 256.  Tile 64 rows x 128 cols, BK=64.
// ---------------------------------------------------------------------------
__global__ __launch_bounds__(256) void k_gemm_h(
        const float* __restrict__ x, const float* __restrict__ W,
        float* __restrict__ h) {
    __shared__ unsigned short Ah[64][72], Al[64][72];
    __shared__ unsigned short Bh[128][72], Bl[128][72];
    const int t = threadIdx.x;
    const int i0 = blockIdx.x * 64;
    const int n0 = blockIdx.y * 128;
    const int lane = t & 63, q = lane >> 4, lm = lane & 15;
    const int w = t >> 6, wm = w >> 1, wn = w & 1;
    const int ar = t >> 2, ac0 = (t & 3) << 4;
    const int bn = t >> 1, bh0 = (t & 1) << 5;
    f32x4 acc[2][4];
#pragma unroll
    for (int mt = 0; mt < 2; ++mt)
#pragma unroll
        for (int nt = 0; nt < 4; ++nt) acc[mt][nt] = (f32x4){0.f, 0.f, 0.f, 0.f};

    for (int kb = 0; kb < DIN; kb += 64) {
        __syncthreads();
        {
            const float4* xp = (const float4*)(x + (size_t)(i0 + ar) * DIN + kb + ac0);
#pragma unroll
            for (int u = 0; u < 4; ++u) {
                float4 v = xp[u];
                unsigned short h0 = f2bf(v.x), h1 = f2bf(v.y), h2 = f2bf(v.z), h3 = f2bf(v.w);
                unsigned short l0 = f2bf(v.x - bf2f(h0)), l1 = f2bf(v.y - bf2f(h1));
                unsigned short l2 = f2bf(v.z - bf2f(h2)), l3 = f2bf(v.w - bf2f(h3));
                *(uint2*)&Ah[ar][ac0 + u * 4] =
                    make_uint2((unsigned)h0 | ((unsigned)h1 << 16), (unsigned)h2 | ((unsigned)h3 << 16));
                *(uint2*)&Al[ar][ac0 + u * 4] =
                    make_uint2((unsigned)l0 | ((unsigned)l1 << 16), (unsigned)l2 | ((unsigned)l3 << 16));
            }
            const float4* wp = (const float4*)(W + (size_t)(n0 + bn) * DIN + kb + bh0);
#pragma unroll
            for (int u = 0; u < 8; ++u) {
                float4 v = wp[u];
                unsigned short h0 = f2bf(v.x), h1 = f2bf(v.y), h2 = f2bf(v.z), h3 = f2bf(v.w);
                unsigned short l0 = f2bf(v.x - bf2f(h0)), l1 = f2bf(v.y - bf2f(h1));
                unsigned short l2 = f2bf(v.z - bf2f(h2)), l3 = f2bf(v.w - bf2f(h3));
                *(uint2*)&Bh[bn][bh0 + u * 4] =
                    make_uint2((unsigned)h0 | ((unsigned)h1 << 16), (unsigned)h2 | ((unsigned)h3 << 16));
                *(uint2*)&Bl[bn][bh0 + u * 4] =
                    make_uint2((unsigned)l0 | ((unsigned)l1 << 16), (unsigned)l2 | ((unsigned)l3 << 16));
            }
        }
        __syncthreads();
#pragma unroll
        for (int ks = 0; ks < 64; ks += 32) {
            short8 fa_h[2], fa_l[2], fb_h[4], fb_l[4];
#pragma unroll
            for (int mt = 0; mt < 2; ++mt) {
                int r = wm * 32 + mt * 16 + lm;
                fa_h[mt] = *(const short8*)&Ah[r][ks + q * 8];
                fa_l[mt] = *(const short8*)&Al[r][ks + q * 8];
            }
#pragma unroll
            for (int nt = 0; nt < 4; ++nt) {
                int c = wn * 64 + nt * 16 + lm;
                fb_h[nt] = *(const short8*)&Bh[c][ks + q * 8];
                fb_l[nt] = *(const short8*)&Bl[c][ks + q * 8];
            }
#pragma unroll
            for (int mt = 0; mt < 2; ++mt)
#pragma unroll
                for (int nt = 0; nt < 4; ++nt) {
                    acc[mt][nt] = __builtin_amdgcn_mfma_f32_16x16x32_bf16(fa_h[mt], fb_h[nt], acc[mt][nt], 0, 0, 0);
                    acc[mt][nt] = __builtin_amdgcn_mfma_f32_16x16x32_bf16(fa_h[mt], fb_l[nt], acc[mt][nt], 0, 0, 0);
                    acc[mt][nt] = __builtin_amdgcn_mfma_f32_16x16x32_bf16(fa_l[mt], fb_h[nt], acc[mt][nt], 0, 0, 0);
                }
        }
    }
#pragma unroll
    for (int mt = 0; mt < 2; ++mt)
#pragma unroll
        for (int nt = 0; nt < 4; ++nt)
#pragma unroll
            for (int rr = 0; rr < 4; ++rr) {
                int row = i0 + wm * 32 + mt * 16 + q * 4 + rr;
                int col = n0 + wn * 64 + nt * 16 + lm;
                h[(size_t)row * DD + col] = acc[mt][nt][rr];
            }
}

// ---------------------------------------------------------------------------
// K3a: s_j = h[j,:] . a[256:512]; one wave per row; block partial max.
// grid 2048, block 256.
// ---------------------------------------------------------------------------
__global__ __launch_bounds__(256) void k_s(
        const float* __restrict__ h, const float* __restrict__ a,
        float* __restrict__ s, float* __restrict__ pmax) {
    __shared__ float wmax[4];
    const int t = threadIdx.x, w = t >> 6, lane = t & 63;
    const int row = blockIdx.x * 4 + w;
    float4 hv = *(const float4*)(h + (size_t)row * DD + lane * 4);
    float4 av = *(const float4*)(a + DD + lane * 4);
    float d = hv.x * av.x + hv.y * av.y + hv.z * av.z + hv.w * av.w;
#pragma unroll
    for (int off = 32; off; off >>= 1) d += __shfl_down(d, off);
    if (lane == 0) { s[row] = d; wmax[w] = d; }
    __syncthreads();
    if (t == 0)
        pmax[blockIdx.x] = fmaxf(fmaxf(wmax[0], wmax[1]), fmaxf(wmax[2], wmax[3]));
}

// ---------------------------------------------------------------------------
// K3b: global max of pmax[2048], then e_j = exp(s_j - M).  grid 1, block 1024.
// ---------------------------------------------------------------------------
__global__ __launch_bounds__(1024) void k_e(
        const float* __restrict__ s, const float* __restrict__ pmax,
        float* __restrict__ e) {
    __shared__ float red[1024];
    const int t = threadIdx.x;
    red[t] = fmaxf(pmax[t], pmax[t + 1024]);
    __syncthreads();
    for (int off = 512; off; off >>= 1) {
        if (t < off) red[t] = fmaxf(red[t], red[t + off]);
        __syncthreads();
    }
    float M = red[0];
    for (int j = t; j < NR; j += 1024) e[j] = expf(s[j] - M);
}

// ---------------------------------------------------------------------------
// K4: g_t[d][j] = bf16(e_j * h[j][d])  (transposed, bf16) via LDS tile.
// grid (128, 4), block 256.
// ---------------------------------------------------------------------------
__global__ __launch_bounds__(256) void k_gt(
        const float* __restrict__ h, const float* __restrict__ e,
        unsigned short* __restrict__ gt) {
    __shared__ float tile[64][68];
    const int t = threadIdx.x;
    const int j0 = blockIdx.x * 64, d0 = blockIdx.y * 64;
    const int r = t >> 4, c4 = (t & 15) * 4;
#pragma unroll
    for (int rr = 0; rr < 4; ++rr) {
        int row = r + rr * 16;
        *(float4*)&tile[row][c4] = *(const float4*)(h + (size_t)(j0 + row) * DD + d0 + c4);
    }
    __syncthreads();
    float4 ev = *(const float4*)(e + j0 + c4);
#pragma unroll
    for (int rr = 0; rr < 4; ++rr) {
        int dd = r + rr * 16;
        unsigned short o0 = f2bf(ev.x * tile[c4 + 0][dd]);
        unsigned short o1 = f2bf(ev.y * tile[c4 + 1][dd]);
        unsigned short o2 = f2bf(ev.z * tile[c4 + 2][dd]);
        unsigned short o3 = f2bf(ev.w * tile[c4 + 3][dd]);
        *(uint2*)(gt + (size_t)(d0 + dd) * NR + j0 + c4) =
            make_uint2((unsigned)o0 | ((unsigned)o1 << 16), (unsigned)o2 | ((unsigned)o3 << 16));
    }
}

// ---------------------------------------------------------------------------
// K5: num += adj_tile @ g, dnm += adj_tile @ e.  adj in {0,1} exact in bf16.
// grid (64, 4) = 64 row-blocks x 4 k-splits; block 512 (8 waves, 2x4 of 64x64).
// ---------------------------------------------------------------------------
__global__ __launch_bounds__(512) void k_big(
        const int* __restrict__ adj, const unsigned short* __restrict__ gt,
        const float* __restrict__ e, float* __restrict__ num,
        float* __restrict__ dnm) {
    __shared__ unsigned short As[128][72];
    __shared__ unsigned short Bs[256][72];
    const int t = threadIdx.x;
    const int row0 = blockIdx.x * 128;
    const int k0 = blockIdx.y * 2048;
    const int lane = t & 63, q = lane >> 4, lm = lane & 15;
    const int w = t >> 6, wm = w >> 2, wn = w & 3;
    const int ar = t >> 2, ac0 = (t & 3) << 4;
    const int bn = t >> 1, bh0 = (t & 1) << 5;
    f32x4 acc[4][4];
#pragma unroll
    for (int mt = 0; mt < 4; ++mt)
#pragma unroll
        for (int nt = 0; nt < 4; ++nt) acc[mt][nt] = (f32x4){0.f, 0.f, 0.f, 0.f};
    float dsum = 0.f;

    for (int it = 0; it < 32; ++it) {
        const int kb = k0 + it * 64;
        __syncthreads();
        {
            const int4* ap = (const int4*)(adj + (size_t)(row0 + ar) * NR + kb + ac0);
            const float4* ep = (const float4*)(e + kb + ac0);
#pragma unroll
            for (int u = 0; u < 4; ++u) {
                int4 av = ap[u];
                float4 ev = ep[u];
                unsigned p0 = (av.x ? 0x3F80u : 0u) | (av.y ? 0x3F800000u : 0u);
                unsigned p1 = (av.z ? 0x3F80u : 0u) | (av.w ? 0x3F800000u : 0u);
                dsum += (av.x ? ev.x : 0.f) + (av.y ? ev.y : 0.f) +
                        (av.z ? ev.z : 0.f) + (av.w ? ev.w : 0.f);
                *(uint2*)&As[ar][ac0 + u * 4] = make_uint2(p0, p1);
            }
            const int4* gp = (const int4*)(gt + (size_t)bn * NR + kb + bh0);
            int4* bd = (int4*)&Bs[bn][bh0];
#pragma unroll
            for (int u = 0; u < 4; ++u) bd[u] = gp[u];
        }
        __syncthreads();
#pragma unroll
        for (int ks = 0; ks < 64; ks += 32) {
            short8 fa[4], fb[4];
#pragma unroll
            for (int mt = 0; mt < 4; ++mt)
                fa[mt] = *(const short8*)&As[wm * 64 + mt * 16 + lm][ks + q * 8];
#pragma unroll
            for (int nt = 0; nt < 4; ++nt)
                fb[nt] = *(const short8*)&Bs[wn * 64 + nt * 16 + lm][ks + q * 8];
#pragma unroll
            for (int mt = 0; mt < 4; ++mt)
#pragma unroll
                for (int nt = 0; nt < 4; ++nt)
                    acc[mt][nt] = __builtin_amdgcn_mfma_f32_16x16x32_bf16(fa[mt], fb[nt], acc[mt][nt], 0, 0, 0);
        }
    }
    // denom: 4 consecutive lanes share a row
    dsum += __shfl_xor(dsum, 1);
    dsum += __shfl_xor(dsum, 2);
    if ((t & 3) == 0) atomicAdd(&dnm[row0 + ar], dsum);
#pragma unroll
    for (int mt = 0; mt < 4; ++mt)
#pragma unroll
        for (int nt = 0; nt < 4; ++nt)
#pragma unroll
            for (int rr = 0; rr < 4; ++rr) {
                int i = row0 + wm * 64 + mt * 16 + q * 4 + rr;
                int d = wn * 64 + nt * 16 + lm;
                atomicAdd(&num[(size_t)i * DD + d], acc[mt][nt][rr]);
            }
}

// ---------------------------------------------------------------------------
// K5b: out0 = elu(num/denom), invd = 1/denom.  grid 2048, block 256.
// ---------------------------------------------------------------------------
__global__ __launch_bounds__(256) void k_fin(
        const float* __restrict__ num, const float* __restrict__ dnm,
        float* __restrict__ out0, float* __restrict__ invd) {
    const int idx = blockIdx.x * 256 + threadIdx.x;
    const int i = idx >> 6, d4 = (idx & 63) << 2;
    float inv = 1.0f / dnm[i];
    float4 nm = *(const float4*)(num + (size_t)i * DD + d4);
    float4 o;
    float z;
    z = nm.x * inv; o.x = z > 0.f ? z : expm1f(z);
    z = nm.y * inv; o.y = z > 0.f ? z : expm1f(z);
    z = nm.z * inv; o.z = z > 0.f ? z : expm1f(z);
    z = nm.w * inv; o.w = z > 0.f ? z : expm1f(z);
    *(float4*)(out0 + (size_t)i * DD + d4) = o;
    if (d4 == 0) invd[i] = inv;
}

// ---------------------------------------------------------------------------
// K6: alpha[i][j] = adj ? e_j * invd_i : 0.  grid 65536, block 256.
// ---------------------------------------------------------------------------
__global__ __launch_bounds__(256) void k_alpha(
        const int* __restrict__ adj, const float* __restrict__ e,
        const float* __restrict__ invd, float* __restrict__ alpha) {
    const size_t idx = (size_t)blockIdx.x * 256 + threadIdx.x;
    const int i = (int)(idx >> 11);
    const int jg = (int)(idx & 2047);
    int4 av = ((const int4*)adj)[idx];
    float4 ev = ((const float4*)e)[jg];
    float inv = invd[i];
    float4 o;
    o.x = av.x ? ev.x * inv : 0.f;
    o.y = av.y ? ev.y * inv : 0.f;
    o.z = av.z ? ev.z * inv : 0.f;
    o.w = av.w ? ev.w * inv : 0.f;
    ((float4*)alpha)[idx] = o;
}

// ---------------------------------------------------------------------------
extern "C" void kernel_launch(void* const* d_in, const int* in_sizes, int n_in,
                              void* d_out, int out_size, void* d_ws, size_t ws_size,
                              hipStream_t stream) {
    const float* x = (const float*)d_in[0];
    const int* adj = (const int*)d_in[1];
    const float* W = (const float*)d_in[2];
    const float* a = (const float*)d_in[3];
    float* out0 = (float*)d_out;
    float* alpha = (float*)d_out + (size_t)NR * DD;

    char* ws = (char*)d_ws;
    float* h            = (float*)(ws + 0);          //  8,388,608 B
    float* s            = (float*)(ws + 8388608);    //     32,768 B
    float* pmax         = (float*)(ws + 8421376);    //      8,192 B
    float* e            = (float*)(ws + 8429568);    //     32,768 B
    float* invd         = (float*)(ws + 8462336);    //     32,768 B
    float* dnm          = (float*)(ws + 8495104);    //     32,768 B
    unsigned short* gt  = (unsigned short*)(ws + 8527872);  // 4,194,304 B
    float* num          = (float*)(ws + 12722176);   //  8,388,608 B  (end ~21.1 MB)

    hipMemsetAsync(num, 0, (size_t)NR * DD * sizeof(float), stream);
    hipMemsetAsync(dnm, 0, NR * sizeof(float), stream);

    k_gemm_h<<<dim3(128, 2), 256, 0, stream>>>(x, W, h);
    k_s<<<2048, 256, 0, stream>>>(h, a, s, pmax);
    k_e<<<1, 1024, 0, stream>>>(s, pmax, e);
    k_gt<<<dim3(128, 4), 256, 0, stream>>>(h, e, gt);
    k_big<<<dim3(64, 4), 512, 0, stream>>>(adj, gt, e, num, dnm);
    k_fin<<<2048, 256, 0, stream>>>(num, dnm, out0, invd);
    k_alpha<<<65536, 256, 0, stream>>>(adj, e, invd, alpha);
}